// Round 4
// baseline (407.585 us; speedup 1.0000x reference)
//
#include <hip/hip_runtime.h>
#include <hip/hip_bf16.h>
#include <stdint.h>

// ---------------------------------------------------------------------------
// MultiHeadSeqAttention (Transformer-XL style sliding-window rel-pos attention)
// HID=1024, NHEADS=16, HEAD=64, MEM=512, LIM=2048, B=8
// logit(m,n) = q[m]·k[n] + q[m]·pe[:,n-m],  n-m in [0,2048)
// ---------------------------------------------------------------------------

typedef __attribute__((ext_vector_type(8))) __bf16 bfrag;   // MFMA A/B operand
typedef __attribute__((ext_vector_type(4))) float f4;       // MFMA C/D

#define DEVFN static __device__ __forceinline__

DEVFN void glds16(const void* g, void* l) {
  __builtin_amdgcn_global_load_lds((const __attribute__((address_space(1))) void*)g,
                                   (__attribute__((address_space(3))) void*)l, 16, 0, 0);
}

DEVFN bfrag cvt8(const float* p) {
  f4 a = *(const f4*)p;
  f4 b = *(const f4*)(p + 4);
  bfrag v;
  v[0] = (__bf16)a.x; v[1] = (__bf16)a.y; v[2] = (__bf16)a.z; v[3] = (__bf16)a.w;
  v[4] = (__bf16)b.x; v[5] = (__bf16)b.y; v[6] = (__bf16)b.z; v[7] = (__bf16)b.w;
  return v;
}

// ------------------ fp32 -> bf16 convert, 4 weights in one launch ----------
__global__ __launch_bounds__(256) void conv4(const float* __restrict__ a0, const float* __restrict__ a1,
                                             const float* __restrict__ a2, const float* __restrict__ a3,
                                             __bf16* __restrict__ d0, __bf16* __restrict__ d1,
                                             __bf16* __restrict__ d2, __bf16* __restrict__ d3) {
  int bx = blockIdx.x;
  int sel = bx >> 9;
  const float* s = sel == 0 ? a0 : sel == 1 ? a1 : sel == 2 ? a2 : a3;
  __bf16* d = sel == 0 ? d0 : sel == 1 ? d1 : sel == 2 ? d2 : d3;
  int i = ((bx & 511) * 256 + (int)threadIdx.x) * 8;   // 512*256*8 = 1M exactly
  *(bfrag*)(d + i) = cvt8(s + i);
}

// ------------------ fp32 -> bf16 convert for q/k/v inputs ------------------
__global__ __launch_bounds__(256) void convin(const float* __restrict__ q, const float* __restrict__ k,
                                              const float* __restrict__ v,
                                              __bf16* __restrict__ qd, __bf16* __restrict__ kd,
                                              __bf16* __restrict__ vd) {
  int bx = blockIdx.x;
  const float* s; __bf16* d; int lb;
  if (bx < 2048)       { s = q; d = qd; lb = bx; }
  else if (bx < 12288) { s = k; d = kd; lb = bx - 2048; }
  else                 { s = v; d = vd; lb = bx - 12288; }
  int i = (lb * 256 + (int)threadIdx.x) * 8;
  *(bfrag*)(d + i) = cvt8(s + i);
}

// ---------------- transposed + zero-padded positional table ----------------
__global__ __launch_bounds__(256) void pek(const float* __restrict__ pe,
                                           __bf16* __restrict__ peT) {
  int i = blockIdx.x * 256 + threadIdx.x;   // grid covers 64*2048 + 128*64 exactly
  if (i < 64 * 2048) {
    int d = i >> 11, l = i & 2047;
    peT[(size_t)(l + 64) * 64 + d] = (__bf16)pe[i];
  } else {
    int zi = i - 64 * 2048;
    int row = zi >> 6, dd = zi & 63;
    int r = row < 64 ? row : (2112 + row - 64);
    peT[(size_t)r * 64 + dd] = (__bf16)0.f;
  }
}

// ---------------------------------------------------------------------------
// projk8: fused q/k/v projection, 256x256 tile, BK=64, 8 waves, deep pipeline.
// 2 LDS K-tile slots (128 KiB). While computing kt (4 phases x 16 MFMA), the
// 8 global_load_lds for kt+1 are issued in phases 0-1 and waited with ONE
// vmcnt(0) at phase 3 (~700cy of MFMA cover). Race ledger: writes go to slot
// s^1; all reads of slot s are register-complete before each wave's q2 MFMA,
// and the closing barrier precedes the next kt's writes.
// ---------------------------------------------------------------------------
DEVFN bfrag rdfrag(const __bf16* L, int row, int kc, int g) {
  return *(const bfrag*)&L[row * 64 + (((g + 4 * kc) ^ (row & 7)) << 3)];
}

__global__ __launch_bounds__(512, 2) void projk8(const __bf16* __restrict__ qbf,
                                                 const __bf16* __restrict__ kbf,
                                                 const __bf16* __restrict__ vbf,
                                                 const __bf16* __restrict__ Wqb,
                                                 const __bf16* __restrict__ Wkb,
                                                 const __bf16* __restrict__ Wvb,
                                                 __bf16* __restrict__ qws,
                                                 __bf16* __restrict__ kws,
                                                 __bf16* __restrict__ vtws) {
  __shared__ alignas(16) __bf16 AL[2][256 * 64];   // 64 KiB
  __shared__ alignas(16) __bf16 BL[2][256 * 64];   // 64 KiB

  int bx = blockIdx.x;                       // 704 blocks = 8*88
  int v = (bx & 7) * 88 + (bx >> 3);         // XCD-aware swizzle
  int rt = v >> 2, ct = v & 3;

  const __bf16* A; const __bf16* W; __bf16* C; int lrt, S, trans;
  if (rt < 16)      { A = qbf; W = Wqb; C = qws;  lrt = rt;      S = 512;  trans = 0; }
  else if (rt < 96) { A = kbf; W = Wkb; C = kws;  lrt = rt - 16; S = 2560; trans = 0; }
  else              { A = vbf; W = Wvb; C = vtws; lrt = rt - 96; S = 2560; trans = 1; }
  const int r0 = lrt * 256, c0 = ct * 256;
  const size_t aoff = (size_t)r0 * 1024, boff = (size_t)c0 * 1024;

  const int tid = threadIdx.x;
  const int lane = tid & 63, wv = tid >> 6;
  const int wr = wv >> 2, wc = wv & 3;       // 2 M x 4 N waves; wave C = 128x64
  const int g = lane >> 4, cl = lane & 15;

  // stage half h (h=0: rows 0..127, h=1: rows 128..255) of K-tile at k0
  auto stage_half = [&](int s, int k0, int h) {
#pragma unroll
    for (int j = 0; j < 2; ++j) {
      int slot = h * 1024 + j * 512 + tid;
      int row = slot >> 3, ch = slot & 7;
      size_t gof = (size_t)row * 1024 + k0 + ((ch ^ (row & 7)) << 3);
      glds16(A + aoff + gof, &AL[s][slot << 3]);
      glds16(W + boff + gof, &BL[s][slot << 3]);
    }
  };

  f4 acc[8][4] = {};

  // prologue: fully stage K-tile 0
  stage_half(0, 0, 0);
  stage_half(0, 0, 1);
  asm volatile("s_waitcnt vmcnt(0)" ::: "memory");
  __builtin_amdgcn_s_barrier();

  for (int kt = 0; kt < 16; ++kt) {
    const int s = kt & 1;
    const __bf16* As = AL[s];
    const __bf16* Bs = BL[s];
    const int k0n = (kt + 1) * 64;
    bfrag af[8], b01[4], b23[4];

    // ---- phase 0: A m0-3 + B n0-1 reads; prefetch half 0 of kt+1
#pragma unroll
    for (int mf = 0; mf < 4; ++mf)
#pragma unroll
      for (int kc = 0; kc < 2; ++kc)
        af[mf * 2 + kc] = rdfrag(As, wr * 128 + mf * 16 + cl, kc, g);
#pragma unroll
    for (int nf = 0; nf < 2; ++nf)
#pragma unroll
      for (int kc = 0; kc < 2; ++kc)
        b01[nf * 2 + kc] = rdfrag(Bs, wc * 64 + nf * 16 + cl, kc, g);
    if (kt < 15) stage_half(s ^ 1, k0n, 0);
    __builtin_amdgcn_s_barrier();
    __builtin_amdgcn_s_setprio(1);
#pragma unroll
    for (int mf = 0; mf < 4; ++mf)
#pragma unroll
      for (int nf = 0; nf < 2; ++nf)
#pragma unroll
        for (int kc = 0; kc < 2; ++kc)
          acc[mf][nf] = __builtin_amdgcn_mfma_f32_16x16x32_bf16(
              af[mf * 2 + kc], b01[nf * 2 + kc], acc[mf][nf], 0, 0, 0);
    __builtin_amdgcn_s_setprio(0);
    __builtin_amdgcn_s_barrier();

    // ---- phase 1: B n2-3 reads; prefetch half 1 of kt+1
#pragma unroll
    for (int nf = 0; nf < 2; ++nf)
#pragma unroll
      for (int kc = 0; kc < 2; ++kc)
        b23[nf * 2 + kc] = rdfrag(Bs, wc * 64 + (2 + nf) * 16 + cl, kc, g);
    if (kt < 15) stage_half(s ^ 1, k0n, 1);
    __builtin_amdgcn_s_barrier();
    __builtin_amdgcn_s_setprio(1);
#pragma unroll
    for (int mf = 0; mf < 4; ++mf)
#pragma unroll
      for (int nf = 0; nf < 2; ++nf)
#pragma unroll
        for (int kc = 0; kc < 2; ++kc)
          acc[mf][2 + nf] = __builtin_amdgcn_mfma_f32_16x16x32_bf16(
              af[mf * 2 + kc], b23[nf * 2 + kc], acc[mf][2 + nf], 0, 0, 0);
    __builtin_amdgcn_s_setprio(0);
    __builtin_amdgcn_s_barrier();

    // ---- phase 2: A m4-7 reads (b01 held in regs)
#pragma unroll
    for (int mf = 0; mf < 4; ++mf)
#pragma unroll
      for (int kc = 0; kc < 2; ++kc)
        af[mf * 2 + kc] = rdfrag(As, wr * 128 + (4 + mf) * 16 + cl, kc, g);
    __builtin_amdgcn_s_barrier();
    __builtin_amdgcn_s_setprio(1);
#pragma unroll
    for (int mf = 0; mf < 4; ++mf)
#pragma unroll
      for (int nf = 0; nf < 2; ++nf)
#pragma unroll
        for (int kc = 0; kc < 2; ++kc)
          acc[4 + mf][nf] = __builtin_amdgcn_mfma_f32_16x16x32_bf16(
              af[mf * 2 + kc], b01[nf * 2 + kc], acc[4 + mf][nf], 0, 0, 0);
    __builtin_amdgcn_s_setprio(0);
    __builtin_amdgcn_s_barrier();

    // ---- phase 3: no reads (b23 held); single counted wait for kt+1 staging
    __builtin_amdgcn_s_setprio(1);
#pragma unroll
    for (int mf = 0; mf < 4; ++mf)
#pragma unroll
      for (int nf = 0; nf < 2; ++nf)
#pragma unroll
        for (int kc = 0; kc < 2; ++kc)
          acc[4 + mf][2 + nf] = __builtin_amdgcn_mfma_f32_16x16x32_bf16(
              af[mf * 2 + kc], b23[nf * 2 + kc], acc[4 + mf][2 + nf], 0, 0, 0);
    __builtin_amdgcn_s_setprio(0);
    if (kt < 15) asm volatile("s_waitcnt vmcnt(0)" ::: "memory");
    __builtin_amdgcn_s_barrier();
  }

  // epilogue: heads layout (q,k) or transposed (v^T)
  int b = r0 / S;
  int sbase = r0 - b * S;
#pragma unroll
  for (int mf = 0; mf < 8; ++mf)
#pragma unroll
    for (int nf = 0; nf < 4; ++nf) {
      int jg = c0 + wc * 64 + nf * 16 + cl;
      int h = jg >> 6, d = jg & 63;
#pragma unroll
      for (int r = 0; r < 4; ++r) {
        int srow = sbase + wr * 128 + mf * 16 + 4 * g + r;
        size_t dst = trans ? ((size_t)(b * 16 + h) * 64 + d) * 2560 + srow
                           : ((size_t)(b * 16 + h) * S + srow) * 64 + d;
        C[dst] = (__bf16)acc[mf][nf][r];
      }
    }
}

// ------------------------- fp32 A reg-staging (fallback) -------------------
DEVFN void stageA_row(const float* ap, __bf16* lds, int arow, int ahalf) {
  const f4* p = (const f4*)ap;
#pragma unroll
  for (int q = 0; q < 4; ++q) {
    f4 a = p[2 * q], b = p[2 * q + 1];
    bfrag v;
    v[0] = (__bf16)a.x; v[1] = (__bf16)a.y; v[2] = (__bf16)a.z; v[3] = (__bf16)a.w;
    v[4] = (__bf16)b.x; v[5] = (__bf16)b.y; v[6] = (__bf16)b.z; v[7] = (__bf16)b.w;
    int ch = (4 * ahalf + q) ^ (arow & 7);
    *(bfrag*)&lds[arow * 64 + ch * 8] = v;
  }
}

// ---------------- fallback fused q/k/v projection (fp32 A) -----------------
__global__ __launch_bounds__(256) void projk_f32(const float* __restrict__ Aq, const float* __restrict__ Ak,
                                                 const float* __restrict__ Av,
                                                 const __bf16* __restrict__ Wqb, const __bf16* __restrict__ Wkb,
                                                 const __bf16* __restrict__ Wvb,
                                                 __bf16* __restrict__ qws, __bf16* __restrict__ kws,
                                                 __bf16* __restrict__ vtws) {
  __shared__ alignas(16) __bf16 Alds[128 * 64];
  __shared__ alignas(16) __bf16 Blds[128 * 64];
  int bx = blockIdx.x;
  const float* A; const __bf16* B; __bf16* C; int nb, lb, rpb, trans;
  if (bx < 256)       { A = Aq; B = Wqb; C = qws;  lb = bx;        nb = 256;  rpb = 4;  trans = 0; }
  else if (bx < 1536) { A = Ak; B = Wkb; C = kws;  lb = bx - 256;  nb = 1280; rpb = 20; trans = 0; }
  else                { A = Av; B = Wvb; C = vtws; lb = bx - 1536; nb = 1280; rpb = 20; trans = 1; }

  const int tid = threadIdx.x;
  const int lane = tid & 63, wv = tid >> 6;
  const int wr = wv >> 1, wc = wv & 1;
  const int g = lane >> 4, cl = lane & 15;

  int v = (lb & 7) * (nb >> 3) + (lb >> 3);
  const int trow = v >> 3;
  const int r0 = trow * 128, c0 = (v & 7) * 128;

  f4 acc[4][4] = {};

  for (int k0 = 0; k0 < 1024; k0 += 64) {
    __syncthreads();
#pragma unroll
    for (int i = 0; i < 4; ++i) {
      int slot = tid + 256 * i;
      int row = slot >> 3, ch = slot & 7;
      glds16(B + (size_t)(c0 + row) * 1024 + k0 + ((ch ^ (row & 7)) << 3),
             &Blds[slot << 3]);
    }
    stageA_row(A + (size_t)(r0 + (tid >> 1)) * 1024 + k0 + (tid & 1) * 32,
               Alds, tid >> 1, tid & 1);
    __syncthreads();
#pragma unroll
    for (int kc = 0; kc < 2; ++kc) {
      bfrag af[4], bfv[4];
#pragma unroll
      for (int i = 0; i < 4; ++i) {
        int rA = 64 * wr + 16 * i + cl;
        af[i] = *(const bfrag*)&Alds[rA * 64 + (((g + 4 * kc) ^ (rA & 7)) << 3)];
        int rB = 64 * wc + 16 * i + cl;
        bfv[i] = *(const bfrag*)&Blds[rB * 64 + (((g + 4 * kc) ^ (rB & 7)) << 3)];
      }
#pragma unroll
      for (int am = 0; am < 4; ++am)
#pragma unroll
        for (int bn = 0; bn < 4; ++bn)
          acc[am][bn] =
              __builtin_amdgcn_mfma_f32_16x16x32_bf16(af[am], bfv[bn], acc[am][bn], 0, 0, 0);
    }
  }

  int Sseq = rpb << 7;
  int b = trow / rpb;
  int sbase = r0 - b * Sseq;
#pragma unroll
  for (int am = 0; am < 4; ++am)
#pragma unroll
    for (int bn = 0; bn < 4; ++bn) {
      int jg = c0 + 64 * wc + 16 * bn + cl;
      int h = jg >> 6, d = jg & 63;
#pragma unroll
      for (int r = 0; r < 4; ++r) {
        int s = sbase + 64 * wr + 16 * am + 4 * g + r;
        size_t dst = trans ? ((size_t)(b * 16 + h) * 64 + d) * 2560 + s
                           : ((size_t)(b * 16 + h) * Sseq + s) * 64 + d;
        C[dst] = (__bf16)acc[am][bn][r];
      }
    }
}

// -------------------------- output projection (f32 out) --------------------
__global__ __launch_bounds__(256) void gemm_out(const __bf16* __restrict__ A,
                                                const __bf16* __restrict__ B,
                                                float* __restrict__ C) {
  __shared__ alignas(16) __bf16 Alds[128 * 64];
  __shared__ alignas(16) __bf16 Blds[128 * 64];
  const int tid = threadIdx.x;
  const int lane = tid & 63, wv = tid >> 6;
  const int wr = wv >> 1, wc = wv & 1;
  const int g = lane >> 4, cl = lane & 15;

  int bx = blockIdx.x;
  int v = (bx & 7) * 32 + (bx >> 3);
  const int r0 = (v >> 3) * 128, c0 = (v & 7) * 128;

  f4 acc[4][4] = {};
  for (int k0 = 0; k0 < 1024; k0 += 64) {
    __syncthreads();
#pragma unroll
    for (int i = 0; i < 4; ++i) {
      int slot = tid + 256 * i;
      int row = slot >> 3, ch = slot & 7;
      glds16(B + (size_t)(c0 + row) * 1024 + k0 + ((ch ^ (row & 7)) << 3),
             &Blds[slot << 3]);
      glds16(A + (size_t)(r0 + row) * 1024 + k0 + ((ch ^ (row & 7)) << 3),
             &Alds[slot << 3]);
    }
    __syncthreads();
#pragma unroll
    for (int kc = 0; kc < 2; ++kc) {
      bfrag af[4], bfv[4];
#pragma unroll
      for (int i = 0; i < 4; ++i) {
        int rA = 64 * wr + 16 * i + cl;
        af[i] = *(const bfrag*)&Alds[rA * 64 + (((g + 4 * kc) ^ (rA & 7)) << 3)];
        int rB = 64 * wc + 16 * i + cl;
        bfv[i] = *(const bfrag*)&Blds[rB * 64 + (((g + 4 * kc) ^ (rB & 7)) << 3)];
      }
#pragma unroll
      for (int am = 0; am < 4; ++am)
#pragma unroll
        for (int bn = 0; bn < 4; ++bn)
          acc[am][bn] =
              __builtin_amdgcn_mfma_f32_16x16x32_bf16(af[am], bfv[bn], acc[am][bn], 0, 0, 0);
    }
  }
#pragma unroll
  for (int am = 0; am < 4; ++am)
#pragma unroll
    for (int bn = 0; bn < 4; ++bn)
#pragma unroll
      for (int r = 0; r < 4; ++r) {
        int rg = r0 + 64 * wr + 16 * am + 4 * g + r;
        int jg = c0 + 64 * wc + 16 * bn + cl;
        C[(size_t)rg * 1024 + jg] = acc[am][bn][r];
      }
}

// --------------------------- fused window attention ------------------------
#define SCL 0.18033688011112042f   // (1/8) * log2(e)
#define FMX 20.0f

__global__ __launch_bounds__(256) void attnk(const __bf16* __restrict__ qws,
                                             const __bf16* __restrict__ kws,
                                             const __bf16* __restrict__ vtws,
                                             const __bf16* __restrict__ pews,
                                             __bf16* __restrict__ obuf) {
  __shared__ alignas(16) __bf16 Ks[64 * 64];
  __shared__ alignas(16) __bf16 QVs[64 * 64];   // Q (prologue) then V^T tiles
  __shared__ alignas(16) __bf16 PPs[64 * 64];   // PE rows, then P (post-barrier)
  __shared__ alignas(16) __bf16 Pbs[64 * 128];  // pos ring: [jm][l & 127]

  int bx = blockIdx.x;
  int vv = (bx & 7) * 128 + (bx >> 3);          // XCD swizzle
  int bh = vv >> 3, mt = vv & 7;
  int m0 = mt * 64;
  const __bf16* qb = qws + (size_t)bh * 512 * 64;
  const __bf16* kb = kws + (size_t)bh * 2560 * 64;
  const __bf16* vb = vtws + (size_t)bh * 64 * 2560;

  const int tid = threadIdx.x;
  const int lane = tid & 63, w = tid >> 6;
  const int g = lane >> 4, cl = lane & 15;

#pragma unroll
  for (int i = 0; i < 2; ++i) {
    int slot = tid + 256 * i;
    int row = slot >> 3, ch = slot & 7;
    glds16(qb + (size_t)(m0 + row) * 64 + ((ch ^ (row & 7)) << 3), &QVs[slot << 3]);
  }
  __syncthreads();
  bfrag qf_all[4][2];
#pragma unroll
  for (int rb = 0; rb < 4; ++rb) {
    int rq = 16 * rb + cl;
#pragma unroll
    for (int kc = 0; kc < 2; ++kc)
      qf_all[rb][kc] = *(const bfrag*)&QVs[rq * 64 + (((g + 4 * kc) ^ (rq & 7)) << 3)];
  }

  f4 o[4] = {};
  float lsum[4] = {};

  for (int t = 0; t < 33; ++t) {
    int n0 = m0 + 64 * t;
    __syncthreads();
#pragma unroll
    for (int i = 0; i < 2; ++i) {
      int slot = tid + 256 * i;
      int row = slot >> 3, ch = slot & 7;
      glds16(kb + (size_t)(n0 + row) * 64 + ((ch ^ (row & 7)) << 3), &Ks[slot << 3]);
      glds16(vb + (size_t)row * 2560 + n0 + ((ch ^ (row & 7)) << 3), &QVs[slot << 3]);
      glds16(pews + (size_t)(64 * (t + 1) + row) * 64 + ((ch ^ (row & 7)) << 3),
             &PPs[slot << 3]);
    }
    __syncthreads();

    f4 sc[4] = {};
    __builtin_amdgcn_s_setprio(1);
#pragma unroll
    for (int kc = 0; kc < 2; ++kc)
#pragma unroll
      for (int cb = 0; cb < 4; ++cb) {
        int rk = 16 * cb + cl;
        bfrag kf = *(const bfrag*)&Ks[rk * 64 + (((g + 4 * kc) ^ (rk & 7)) << 3)];
        sc[cb] = __builtin_amdgcn_mfma_f32_16x16x32_bf16(qf_all[w][kc], kf, sc[cb], 0, 0, 0);
      }
    f4 pbacc[4] = {};
#pragma unroll
    for (int kc = 0; kc < 2; ++kc) {
      int rp = 16 * w + cl;
      bfrag pf = *(const bfrag*)&PPs[rp * 64 + (((g + 4 * kc) ^ (rp & 7)) << 3)];
#pragma unroll
      for (int rb = 0; rb < 4; ++rb)
        pbacc[rb] = __builtin_amdgcn_mfma_f32_16x16x32_bf16(qf_all[rb][kc], pf, pbacc[rb], 0, 0, 0);
    }
    __builtin_amdgcn_s_setprio(0);
    {
      int half = (t & 1) << 6;
      int c2 = 16 * w + cl;
#pragma unroll
      for (int rb = 0; rb < 4; ++rb)
#pragma unroll
        for (int r = 0; r < 4; ++r)
          Pbs[(16 * rb + 4 * g + r) * 128 + half + c2] = (__bf16)pbacc[rb][r];
    }
    __syncthreads();

    bool edge = (t == 0) || (t == 32);
#pragma unroll
    for (int r = 0; r < 4; ++r) {
      int jm = 16 * w + 4 * g + r;
#pragma unroll
      for (int cb = 0; cb < 4; ++cb) {
        int jn = 16 * cb + cl;
        int l = 64 * t + jn - jm;
        float pv = (float)Pbs[jm * 128 + (l & 127)];
        float ex = fmaf(sc[cb][r] + pv, SCL, -FMX);
        if (edge) ex = ((unsigned)l < 2048u) ? ex : -1e30f;
        float p = __builtin_amdgcn_exp2f(ex);
        lsum[r] += p;
        PPs[jm * 64 + (((jn >> 3) ^ (jm & 7)) << 3) + (jn & 7)] = (__bf16)p;
      }
    }

    __builtin_amdgcn_s_setprio(1);
#pragma unroll
    for (int kc = 0; kc < 2; ++kc) {
      int rp2 = 16 * w + cl;
      bfrag pa = *(const bfrag*)&PPs[rp2 * 64 + (((g + 4 * kc) ^ (rp2 & 7)) << 3)];
#pragma unroll
      for (int cb = 0; cb < 4; ++cb) {
        int rv = 16 * cb + cl;
        bfrag vf = *(const bfrag*)&QVs[rv * 64 + (((g + 4 * kc) ^ (rv & 7)) << 3)];
        o[cb] = __builtin_amdgcn_mfma_f32_16x16x32_bf16(pa, vf, o[cb], 0, 0, 0);
      }
    }
    __builtin_amdgcn_s_setprio(0);
  }

#pragma unroll
  for (int r = 0; r < 4; ++r)
#pragma unroll
    for (int off = 1; off < 16; off <<= 1) lsum[r] += __shfl_xor(lsum[r], off);

  int b = bh >> 4, h = bh & 15;
#pragma unroll
  for (int cb = 0; cb < 4; ++cb)
#pragma unroll
    for (int r = 0; r < 4; ++r) {
      int m = m0 + 16 * w + 4 * g + r;
      int d = 16 * cb + cl;
      obuf[((size_t)(b * 512 + m)) * 1024 + h * 64 + d] = (__bf16)(o[cb][r] / lsum[r]);
    }
}

// ---------------------------------------------------------------------------
extern "C" void kernel_launch(void* const* d_in, const int* in_sizes, int n_in,
                              void* d_out, int out_size, void* d_ws, size_t ws_size,
                              hipStream_t stream) {
  const float* query = (const float*)d_in[0];
  const float* key   = (const float*)d_in[1];
  const float* value = (const float*)d_in[2];
  const float* keype = (const float*)d_in[3];
  const float* Wq    = (const float*)d_in[4];
  const float* Wk    = (const float*)d_in[5];
  const float* Wv    = (const float*)d_in[6];
  const float* Wo    = (const float*)d_in[7];
  float* out = (float*)d_out;
  (void)in_sizes; (void)n_in; (void)out_size;

  char* ws = (char*)d_ws;
  size_t off = 0;
  auto alloc = [&](size_t bytes) {
    void* p = ws + off;
    off += (bytes + 255) & ~(size_t)255;
    return p;
  };
  __bf16* Wqb  = (__bf16*)alloc((size_t)1024 * 1024 * 2);
  __bf16* Wkb  = (__bf16*)alloc((size_t)1024 * 1024 * 2);
  __bf16* Wvb  = (__bf16*)alloc((size_t)1024 * 1024 * 2);
  __bf16* Wob  = (__bf16*)alloc((size_t)1024 * 1024 * 2);
  __bf16* peT  = (__bf16*)alloc((size_t)2176 * 64 * 2);
  __bf16* qws  = (__bf16*)alloc((size_t)128 * 512 * 64 * 2);
  __bf16* kws  = (__bf16*)alloc((size_t)128 * 2560 * 64 * 2);
  __bf16* vtws = (__bf16*)alloc((size_t)128 * 2560 * 64 * 2);

  const size_t NEED = (size_t)194 * 1024 * 1024;
  bool big = ws_size >= NEED;

  conv4<<<2048, 256, 0, stream>>>(Wq, Wk, Wv, Wo, Wqb, Wkb, Wvb, Wob);
  pek<<<544, 256, 0, stream>>>(keype, peT);

  __bf16* obuf;
  if (big) {
    __bf16* qbf = (__bf16*)alloc((size_t)8 * 512 * 1024 * 2);
    __bf16* kbf = (__bf16*)alloc((size_t)8 * 2560 * 1024 * 2);
    __bf16* vbf = (__bf16*)alloc((size_t)8 * 2560 * 1024 * 2);
    obuf = qbf;   // qbf dead after projk8; obuf born at attnk
    convin<<<22528, 256, 0, stream>>>(query, key, value, qbf, kbf, vbf);
    projk8<<<704, 512, 0, stream>>>(qbf, kbf, vbf, Wqb, Wkb, Wvb, qws, kws, vtws);
  } else {
    obuf = (__bf16*)alloc((size_t)4096 * 1024 * 2);
    projk_f32<<<2816, 256, 0, stream>>>(query, key, value, Wqb, Wkb, Wvb,
                                        qws, kws, vtws);
  }

  attnk<<<1024, 256, 0, stream>>>(qws, kws, vtws, peT, obuf);
  gemm_out<<<256, 256, 0, stream>>>(obuf, Wob, out);
}

// Round 5
// 377.919 us; speedup vs baseline: 1.0785x; 1.0785x over previous
//
#include <hip/hip_runtime.h>
#include <hip/hip_bf16.h>
#include <stdint.h>

// ---------------------------------------------------------------------------
// MultiHeadSeqAttention (Transformer-XL style sliding-window rel-pos attention)
// HID=1024, NHEADS=16, HEAD=64, MEM=512, LIM=2048, B=8
// logit(m,n) = q[m]·k[n] + q[m]·pe[:,n-m],  n-m in [0,2048)
// ---------------------------------------------------------------------------

typedef __attribute__((ext_vector_type(8))) __bf16 bfrag;   // MFMA A/B operand
typedef __attribute__((ext_vector_type(4))) float f4;       // MFMA C/D

#define DEVFN static __device__ __forceinline__

DEVFN void glds16(const void* g, void* l) {
  __builtin_amdgcn_global_load_lds((const __attribute__((address_space(1))) void*)g,
                                   (__attribute__((address_space(3))) void*)l, 16, 0, 0);
}

DEVFN bfrag cvt8(const float* p) {
  f4 a = *(const f4*)p;
  f4 b = *(const f4*)(p + 4);
  bfrag v;
  v[0] = (__bf16)a.x; v[1] = (__bf16)a.y; v[2] = (__bf16)a.z; v[3] = (__bf16)a.w;
  v[4] = (__bf16)b.x; v[5] = (__bf16)b.y; v[6] = (__bf16)b.z; v[7] = (__bf16)b.w;
  return v;
}

// ------------------ fp32 -> bf16 convert, 4 weights in one launch ----------
__global__ __launch_bounds__(256) void conv4(const float* __restrict__ a0, const float* __restrict__ a1,
                                             const float* __restrict__ a2, const float* __restrict__ a3,
                                             __bf16* __restrict__ d0, __bf16* __restrict__ d1,
                                             __bf16* __restrict__ d2, __bf16* __restrict__ d3) {
  int bx = blockIdx.x;
  int sel = bx >> 9;
  const float* s = sel == 0 ? a0 : sel == 1 ? a1 : sel == 2 ? a2 : a3;
  __bf16* d = sel == 0 ? d0 : sel == 1 ? d1 : sel == 2 ? d2 : d3;
  int i = ((bx & 511) * 256 + (int)threadIdx.x) * 8;   // 512*256*8 = 1M exactly
  *(bfrag*)(d + i) = cvt8(s + i);
}

// ------------------ fp32 -> bf16 convert for q/k/v inputs ------------------
__global__ __launch_bounds__(256) void convin(const float* __restrict__ q, const float* __restrict__ k,
                                              const float* __restrict__ v,
                                              __bf16* __restrict__ qd, __bf16* __restrict__ kd,
                                              __bf16* __restrict__ vd) {
  int bx = blockIdx.x;
  const float* s; __bf16* d; int lb;
  if (bx < 2048)       { s = q; d = qd; lb = bx; }
  else if (bx < 12288) { s = k; d = kd; lb = bx - 2048; }
  else                 { s = v; d = vd; lb = bx - 12288; }
  int i = (lb * 256 + (int)threadIdx.x) * 8;
  *(bfrag*)(d + i) = cvt8(s + i);
}

// ---------------- transposed + zero-padded positional table ----------------
__global__ __launch_bounds__(256) void pek(const float* __restrict__ pe,
                                           __bf16* __restrict__ peT) {
  int i = blockIdx.x * 256 + threadIdx.x;   // grid covers 64*2048 + 128*64 exactly
  if (i < 64 * 2048) {
    int d = i >> 11, l = i & 2047;
    peT[(size_t)(l + 64) * 64 + d] = (__bf16)pe[i];
  } else {
    int zi = i - 64 * 2048;
    int row = zi >> 6, dd = zi & 63;
    int r = row < 64 ? row : (2112 + row - 64);
    peT[(size_t)r * 64 + dd] = (__bf16)0.f;
  }
}

// ---------------------------------------------------------------------------
// core16: 128x128 tile, BK=64, 16 K-steps, counted-vmcnt pipeline.
// A (HBM, ~900cy) double-buffered; B (weights, L2-hot ~200cy) single-buffered.
// Per iter: issue B(kt) then A(kt+1); s_waitcnt vmcnt(4) completes the 8
// oldest (A(kt)+B(kt)) and leaves A(kt+1)'s 4 in flight across the barrier
// (T4 counted wait; FIFO vmcnt semantics). 2 raw barriers/K-step, no drain.
// Race ledger: slot s^1 writes are issued only after the barrier that closed
// the reads of s^1 (prev iter); B overwrites only after prev reads were
// register-complete (MFMA-forced lgkm waits) + end barrier.
// ---------------------------------------------------------------------------
DEVFN bfrag rdfrag(const __bf16* L, int row, int kc, int g) {
  return *(const bfrag*)&L[row * 64 + (((g + 4 * kc) ^ (row & 7)) << 3)];
}

DEVFN void core16(const __bf16* __restrict__ A, const __bf16* __restrict__ B,
                  __bf16* AL, __bf16* BL, f4 (&acc)[4][4],
                  int tid, int wr, int wc, int g, int cl) {
  auto stageA = [&](int s, int k0) {
#pragma unroll
    for (int j = 0; j < 4; ++j) {
      int slot = j * 256 + tid;
      int row = slot >> 3, ch = slot & 7;
      glds16(A + (size_t)row * 1024 + k0 + ((ch ^ (row & 7)) << 3),
             &AL[s * 8192 + (slot << 3)]);
    }
  };
  auto stageB = [&](int k0) {
#pragma unroll
    for (int j = 0; j < 4; ++j) {
      int slot = j * 256 + tid;
      int row = slot >> 3, ch = slot & 7;
      glds16(B + (size_t)row * 1024 + k0 + ((ch ^ (row & 7)) << 3),
             &BL[slot << 3]);
    }
  };

  stageA(0, 0);
  for (int kt = 0; kt < 16; ++kt) {
    const int s = kt & 1;
    stageB(kt * 64);
    if (kt < 15) {
      stageA(s ^ 1, (kt + 1) * 64);
      asm volatile("s_waitcnt vmcnt(4)" ::: "memory");
    } else {
      asm volatile("s_waitcnt vmcnt(0)" ::: "memory");
    }
    __builtin_amdgcn_s_barrier();
    const __bf16* As = &AL[s * 8192];
#pragma unroll
    for (int kc = 0; kc < 2; ++kc) {
      bfrag af[4], bf[4];
#pragma unroll
      for (int i = 0; i < 4; ++i) {
        af[i] = rdfrag(As, 64 * wr + 16 * i + cl, kc, g);
        bf[i] = rdfrag(BL, 64 * wc + 16 * i + cl, kc, g);
      }
      __builtin_amdgcn_s_setprio(1);
#pragma unroll
      for (int am = 0; am < 4; ++am)
#pragma unroll
        for (int bn = 0; bn < 4; ++bn)
          acc[am][bn] =
              __builtin_amdgcn_mfma_f32_16x16x32_bf16(af[am], bf[bn], acc[am][bn], 0, 0, 0);
      __builtin_amdgcn_s_setprio(0);
    }
    __builtin_amdgcn_s_barrier();
  }
}

// ---------------- fused q/k/v projection: C = A @ W^T, heads layout --------
// grid 2816: [0,256) q (S=512) | [256,1536) k (S=2560) | [1536,2816) v -> v^T
__global__ __launch_bounds__(256) void projk_c(const __bf16* __restrict__ Aq, const __bf16* __restrict__ Ak,
                                               const __bf16* __restrict__ Av,
                                               const __bf16* __restrict__ Wqb, const __bf16* __restrict__ Wkb,
                                               const __bf16* __restrict__ Wvb,
                                               __bf16* __restrict__ qws, __bf16* __restrict__ kws,
                                               __bf16* __restrict__ vtws) {
  __shared__ alignas(16) __bf16 AL[2 * 128 * 64];   // 32 KiB (A dbuf)
  __shared__ alignas(16) __bf16 BL[128 * 64];       // 16 KiB (B single)
  int bx = blockIdx.x;
  const __bf16* A; const __bf16* B; __bf16* C; int nb, lb, rpb, trans;
  if (bx < 256)       { A = Aq; B = Wqb; C = qws;  lb = bx;        nb = 256;  rpb = 4;  trans = 0; }
  else if (bx < 1536) { A = Ak; B = Wkb; C = kws;  lb = bx - 256;  nb = 1280; rpb = 20; trans = 0; }
  else                { A = Av; B = Wvb; C = vtws; lb = bx - 1536; nb = 1280; rpb = 20; trans = 1; }

  const int tid = threadIdx.x;
  const int lane = tid & 63, wv = tid >> 6;
  const int wr = wv >> 1, wc = wv & 1;
  const int g = lane >> 4, cl = lane & 15;

  int v = (lb & 7) * (nb >> 3) + (lb >> 3);   // XCD-aware swizzle (nb % 8 == 0)
  const int trow = v >> 3;
  const int r0 = trow * 128, c0 = (v & 7) * 128;

  f4 acc[4][4] = {};
  core16(A + (size_t)r0 * 1024, B + (size_t)c0 * 1024, AL, BL, acc,
         tid, wr, wc, g, cl);

  int Sseq = rpb << 7;
  int b = trow / rpb;
  int sbase = r0 - b * Sseq;
#pragma unroll
  for (int am = 0; am < 4; ++am)
#pragma unroll
    for (int bn = 0; bn < 4; ++bn) {
      int jg = c0 + 64 * wc + 16 * bn + cl;
      int h = jg >> 6, d = jg & 63;
#pragma unroll
      for (int r = 0; r < 4; ++r) {
        int s = sbase + 64 * wr + 16 * am + 4 * g + r;
        size_t dst = trans ? ((size_t)(b * 16 + h) * 64 + d) * 2560 + s
                           : ((size_t)(b * 16 + h) * Sseq + s) * 64 + d;
        C[dst] = (__bf16)acc[am][bn][r];
      }
    }
}

// ------------------------- fp32 A reg-staging (fallback) -------------------
DEVFN void stageA_row(const float* ap, __bf16* lds, int arow, int ahalf) {
  const f4* p = (const f4*)ap;
#pragma unroll
  for (int q = 0; q < 4; ++q) {
    f4 a = p[2 * q], b = p[2 * q + 1];
    bfrag v;
    v[0] = (__bf16)a.x; v[1] = (__bf16)a.y; v[2] = (__bf16)a.z; v[3] = (__bf16)a.w;
    v[4] = (__bf16)b.x; v[5] = (__bf16)b.y; v[6] = (__bf16)b.z; v[7] = (__bf16)b.w;
    int ch = (4 * ahalf + q) ^ (arow & 7);
    *(bfrag*)&lds[arow * 64 + ch * 8] = v;
  }
}

// ---------------- fallback fused q/k/v projection (fp32 A) -----------------
__global__ __launch_bounds__(256) void projk_f32(const float* __restrict__ Aq, const float* __restrict__ Ak,
                                                 const float* __restrict__ Av,
                                                 const __bf16* __restrict__ Wqb, const __bf16* __restrict__ Wkb,
                                                 const __bf16* __restrict__ Wvb,
                                                 __bf16* __restrict__ qws, __bf16* __restrict__ kws,
                                                 __bf16* __restrict__ vtws) {
  __shared__ alignas(16) __bf16 Alds[128 * 64];
  __shared__ alignas(16) __bf16 Blds[128 * 64];
  int bx = blockIdx.x;
  const float* A; const __bf16* B; __bf16* C; int nb, lb, rpb, trans;
  if (bx < 256)       { A = Aq; B = Wqb; C = qws;  lb = bx;        nb = 256;  rpb = 4;  trans = 0; }
  else if (bx < 1536) { A = Ak; B = Wkb; C = kws;  lb = bx - 256;  nb = 1280; rpb = 20; trans = 0; }
  else                { A = Av; B = Wvb; C = vtws; lb = bx - 1536; nb = 1280; rpb = 20; trans = 1; }

  const int tid = threadIdx.x;
  const int lane = tid & 63, wv = tid >> 6;
  const int wr = wv >> 1, wc = wv & 1;
  const int g = lane >> 4, cl = lane & 15;

  int v = (lb & 7) * (nb >> 3) + (lb >> 3);
  const int trow = v >> 3;
  const int r0 = trow * 128, c0 = (v & 7) * 128;

  f4 acc[4][4] = {};

  for (int k0 = 0; k0 < 1024; k0 += 64) {
    __syncthreads();
#pragma unroll
    for (int i = 0; i < 4; ++i) {
      int slot = tid + 256 * i;
      int row = slot >> 3, ch = slot & 7;
      glds16(B + (size_t)(c0 + row) * 1024 + k0 + ((ch ^ (row & 7)) << 3),
             &Blds[slot << 3]);
    }
    stageA_row(A + (size_t)(r0 + (tid >> 1)) * 1024 + k0 + (tid & 1) * 32,
               Alds, tid >> 1, tid & 1);
    __syncthreads();
#pragma unroll
    for (int kc = 0; kc < 2; ++kc) {
      bfrag af[4], bfv[4];
#pragma unroll
      for (int i = 0; i < 4; ++i) {
        int rA = 64 * wr + 16 * i + cl;
        af[i] = *(const bfrag*)&Alds[rA * 64 + (((g + 4 * kc) ^ (rA & 7)) << 3)];
        int rB = 64 * wc + 16 * i + cl;
        bfv[i] = *(const bfrag*)&Blds[rB * 64 + (((g + 4 * kc) ^ (rB & 7)) << 3)];
      }
#pragma unroll
      for (int am = 0; am < 4; ++am)
#pragma unroll
        for (int bn = 0; bn < 4; ++bn)
          acc[am][bn] =
              __builtin_amdgcn_mfma_f32_16x16x32_bf16(af[am], bfv[bn], acc[am][bn], 0, 0, 0);
    }
  }

  int Sseq = rpb << 7;
  int b = trow / rpb;
  int sbase = r0 - b * Sseq;
#pragma unroll
  for (int am = 0; am < 4; ++am)
#pragma unroll
    for (int bn = 0; bn < 4; ++bn) {
      int jg = c0 + 64 * wc + 16 * bn + cl;
      int h = jg >> 6, d = jg & 63;
#pragma unroll
      for (int r = 0; r < 4; ++r) {
        int s = sbase + 64 * wr + 16 * am + 4 * g + r;
        size_t dst = trans ? ((size_t)(b * 16 + h) * 64 + d) * 2560 + s
                           : ((size_t)(b * 16 + h) * Sseq + s) * 64 + d;
        C[dst] = (__bf16)acc[am][bn][r];
      }
    }
}

// -------------------------- output projection (f32 out) --------------------
__global__ __launch_bounds__(256) void gemm_out(const __bf16* __restrict__ A,
                                                const __bf16* __restrict__ B,
                                                float* __restrict__ C) {
  __shared__ alignas(16) __bf16 AL[2 * 128 * 64];
  __shared__ alignas(16) __bf16 BL[128 * 64];
  const int tid = threadIdx.x;
  const int lane = tid & 63, wv = tid >> 6;
  const int wr = wv >> 1, wc = wv & 1;
  const int g = lane >> 4, cl = lane & 15;

  int bx = blockIdx.x;
  int v = (bx & 7) * 32 + (bx >> 3);
  const int r0 = (v >> 3) * 128, c0 = (v & 7) * 128;

  f4 acc[4][4] = {};
  core16(A + (size_t)r0 * 1024, B + (size_t)c0 * 1024, AL, BL, acc,
         tid, wr, wc, g, cl);

#pragma unroll
  for (int am = 0; am < 4; ++am)
#pragma unroll
    for (int bn = 0; bn < 4; ++bn)
#pragma unroll
      for (int r = 0; r < 4; ++r) {
        int rg = r0 + 64 * wr + 16 * am + 4 * g + r;
        int jg = c0 + 64 * wc + 16 * bn + cl;
        C[(size_t)rg * 1024 + jg] = acc[am][bn][r];
      }
}

// --------------------------- fused window attention ------------------------
#define SCL 0.18033688011112042f   // (1/8) * log2(e)
#define FMX 20.0f

__global__ __launch_bounds__(256) void attnk(const __bf16* __restrict__ qws,
                                             const __bf16* __restrict__ kws,
                                             const __bf16* __restrict__ vtws,
                                             const __bf16* __restrict__ pews,
                                             __bf16* __restrict__ obuf) {
  __shared__ alignas(16) __bf16 Ks[64 * 64];
  __shared__ alignas(16) __bf16 QVs[64 * 64];   // Q (prologue) then V^T tiles
  __shared__ alignas(16) __bf16 PPs[64 * 64];   // PE rows, then P (post-barrier)
  __shared__ alignas(16) __bf16 Pbs[64 * 128];  // pos ring: [jm][l & 127]

  int bx = blockIdx.x;
  int vv = (bx & 7) * 128 + (bx >> 3);          // XCD swizzle
  int bh = vv >> 3, mt = vv & 7;
  int m0 = mt * 64;
  const __bf16* qb = qws + (size_t)bh * 512 * 64;
  const __bf16* kb = kws + (size_t)bh * 2560 * 64;
  const __bf16* vb = vtws + (size_t)bh * 64 * 2560;

  const int tid = threadIdx.x;
  const int lane = tid & 63, w = tid >> 6;
  const int g = lane >> 4, cl = lane & 15;

#pragma unroll
  for (int i = 0; i < 2; ++i) {
    int slot = tid + 256 * i;
    int row = slot >> 3, ch = slot & 7;
    glds16(qb + (size_t)(m0 + row) * 64 + ((ch ^ (row & 7)) << 3), &QVs[slot << 3]);
  }
  __syncthreads();
  bfrag qf_all[4][2];
#pragma unroll
  for (int rb = 0; rb < 4; ++rb) {
    int rq = 16 * rb + cl;
#pragma unroll
    for (int kc = 0; kc < 2; ++kc)
      qf_all[rb][kc] = *(const bfrag*)&QVs[rq * 64 + (((g + 4 * kc) ^ (rq & 7)) << 3)];
  }

  f4 o[4] = {};
  float lsum[4] = {};

  for (int t = 0; t < 33; ++t) {
    int n0 = m0 + 64 * t;
    __syncthreads();
#pragma unroll
    for (int i = 0; i < 2; ++i) {
      int slot = tid + 256 * i;
      int row = slot >> 3, ch = slot & 7;
      glds16(kb + (size_t)(n0 + row) * 64 + ((ch ^ (row & 7)) << 3), &Ks[slot << 3]);
      glds16(vb + (size_t)row * 2560 + n0 + ((ch ^ (row & 7)) << 3), &QVs[slot << 3]);
      glds16(pews + (size_t)(64 * (t + 1) + row) * 64 + ((ch ^ (row & 7)) << 3),
             &PPs[slot << 3]);
    }
    __syncthreads();

    f4 sc[4] = {};
    __builtin_amdgcn_s_setprio(1);
#pragma unroll
    for (int kc = 0; kc < 2; ++kc)
#pragma unroll
      for (int cb = 0; cb < 4; ++cb) {
        int rk = 16 * cb + cl;
        bfrag kf = *(const bfrag*)&Ks[rk * 64 + (((g + 4 * kc) ^ (rk & 7)) << 3)];
        sc[cb] = __builtin_amdgcn_mfma_f32_16x16x32_bf16(qf_all[w][kc], kf, sc[cb], 0, 0, 0);
      }
    f4 pbacc[4] = {};
#pragma unroll
    for (int kc = 0; kc < 2; ++kc) {
      int rp = 16 * w + cl;
      bfrag pf = *(const bfrag*)&PPs[rp * 64 + (((g + 4 * kc) ^ (rp & 7)) << 3)];
#pragma unroll
      for (int rb = 0; rb < 4; ++rb)
        pbacc[rb] = __builtin_amdgcn_mfma_f32_16x16x32_bf16(qf_all[rb][kc], pf, pbacc[rb], 0, 0, 0);
    }
    __builtin_amdgcn_s_setprio(0);
    {
      int half = (t & 1) << 6;
      int c2 = 16 * w + cl;
#pragma unroll
      for (int rb = 0; rb < 4; ++rb)
#pragma unroll
        for (int r = 0; r < 4; ++r)
          Pbs[(16 * rb + 4 * g + r) * 128 + half + c2] = (__bf16)pbacc[rb][r];
    }
    __syncthreads();

    bool edge = (t == 0) || (t == 32);
#pragma unroll
    for (int r = 0; r < 4; ++r) {
      int jm = 16 * w + 4 * g + r;
#pragma unroll
      for (int cb = 0; cb < 4; ++cb) {
        int jn = 16 * cb + cl;
        int l = 64 * t + jn - jm;
        float pv = (float)Pbs[jm * 128 + (l & 127)];
        float ex = fmaf(sc[cb][r] + pv, SCL, -FMX);
        if (edge) ex = ((unsigned)l < 2048u) ? ex : -1e30f;
        float p = __builtin_amdgcn_exp2f(ex);
        lsum[r] += p;
        PPs[jm * 64 + (((jn >> 3) ^ (jm & 7)) << 3) + (jn & 7)] = (__bf16)p;
      }
    }

    __builtin_amdgcn_s_setprio(1);
#pragma unroll
    for (int kc = 0; kc < 2; ++kc) {
      int rp2 = 16 * w + cl;
      bfrag pa = *(const bfrag*)&PPs[rp2 * 64 + (((g + 4 * kc) ^ (rp2 & 7)) << 3)];
#pragma unroll
      for (int cb = 0; cb < 4; ++cb) {
        int rv = 16 * cb + cl;
        bfrag vf = *(const bfrag*)&QVs[rv * 64 + (((g + 4 * kc) ^ (rv & 7)) << 3)];
        o[cb] = __builtin_amdgcn_mfma_f32_16x16x32_bf16(pa, vf, o[cb], 0, 0, 0);
      }
    }
    __builtin_amdgcn_s_setprio(0);
  }

#pragma unroll
  for (int r = 0; r < 4; ++r)
#pragma unroll
    for (int off = 1; off < 16; off <<= 1) lsum[r] += __shfl_xor(lsum[r], off);

  int b = bh >> 4, h = bh & 15;
#pragma unroll
  for (int cb = 0; cb < 4; ++cb)
#pragma unroll
    for (int r = 0; r < 4; ++r) {
      int m = m0 + 16 * w + 4 * g + r;
      int d = 16 * cb + cl;
      obuf[((size_t)(b * 512 + m)) * 1024 + h * 64 + d] = (__bf16)(o[cb][r] / lsum[r]);
    }
}

// ---------------------------------------------------------------------------
extern "C" void kernel_launch(void* const* d_in, const int* in_sizes, int n_in,
                              void* d_out, int out_size, void* d_ws, size_t ws_size,
                              hipStream_t stream) {
  const float* query = (const float*)d_in[0];
  const float* key   = (const float*)d_in[1];
  const float* value = (const float*)d_in[2];
  const float* keype = (const float*)d_in[3];
  const float* Wq    = (const float*)d_in[4];
  const float* Wk    = (const float*)d_in[5];
  const float* Wv    = (const float*)d_in[6];
  const float* Wo    = (const float*)d_in[7];
  float* out = (float*)d_out;
  (void)in_sizes; (void)n_in; (void)out_size;

  char* ws = (char*)d_ws;
  size_t off = 0;
  auto alloc = [&](size_t bytes) {
    void* p = ws + off;
    off += (bytes + 255) & ~(size_t)255;
    return p;
  };
  __bf16* Wqb  = (__bf16*)alloc((size_t)1024 * 1024 * 2);
  __bf16* Wkb  = (__bf16*)alloc((size_t)1024 * 1024 * 2);
  __bf16* Wvb  = (__bf16*)alloc((size_t)1024 * 1024 * 2);
  __bf16* Wob  = (__bf16*)alloc((size_t)1024 * 1024 * 2);
  __bf16* peT  = (__bf16*)alloc((size_t)2176 * 64 * 2);
  __bf16* qws  = (__bf16*)alloc((size_t)128 * 512 * 64 * 2);
  __bf16* kws  = (__bf16*)alloc((size_t)128 * 2560 * 64 * 2);
  __bf16* vtws = (__bf16*)alloc((size_t)128 * 2560 * 64 * 2);

  const size_t NEED = (size_t)194 * 1024 * 1024;
  bool big = ws_size >= NEED;

  conv4<<<2048, 256, 0, stream>>>(Wq, Wk, Wv, Wo, Wqb, Wkb, Wvb, Wob);
  pek<<<544, 256, 0, stream>>>(keype, peT);

  __bf16* obuf;
  if (big) {
    __bf16* qbf = (__bf16*)alloc((size_t)8 * 512 * 1024 * 2);
    __bf16* kbf = (__bf16*)alloc((size_t)8 * 2560 * 1024 * 2);
    __bf16* vbf = (__bf16*)alloc((size_t)8 * 2560 * 1024 * 2);
    obuf = qbf;   // qbf dead after projk_c; obuf born at attnk
    convin<<<22528, 256, 0, stream>>>(query, key, value, qbf, kbf, vbf);
    projk_c<<<2816, 256, 0, stream>>>(qbf, kbf, vbf, Wqb, Wkb, Wvb, qws, kws, vtws);
  } else {
    obuf = (__bf16*)alloc((size_t)4096 * 1024 * 2);
    projk_f32<<<2816, 256, 0, stream>>>(query, key, value, Wqb, Wkb, Wvb,
                                        qws, kws, vtws);
  }

  attnk<<<1024, 256, 0, stream>>>(qws, kws, vtws, peT, obuf);
  gemm_out<<<256, 256, 0, stream>>>(obuf, Wob, out);
}